// Round 13
// baseline (246.310 us; speedup 1.0000x reference)
//
#include <hip/hip_runtime.h>
#include <hip/hip_fp16.h>

#define DIM 256
#define MAXNORM 0.996f      // (1 - 4e-3)/sqrt(c), c=1
#define MINN 1e-15f
#define CLIPV 0.9999999f    // 1 - 1e-7

typedef __attribute__((ext_vector_type(8))) short bf16x8;
typedef __attribute__((ext_vector_type(4))) float f32x4;

__device__ __forceinline__ unsigned short f2bf(float f) {
    unsigned int u = __float_as_uint(f);
    u += 0x7fffu + ((u >> 16) & 1u);   // RNE
    return (unsigned short)(u >> 16);
}
__device__ __forceinline__ float h2f(unsigned short h) {
    return __half2float(__ushort_as_half(h));
}
__device__ __forceinline__ unsigned short f2h(float f) {
    return __half_as_ushort(__float2half(f));
}
__device__ __forceinline__ float wsum(float v) {   // 64-lane sum
    v += __shfl_xor(v, 32);
    v += __shfl_xor(v, 16);
    v += __shfl_xor(v, 8);
    v += __shfl_xor(v, 4);
    v += __shfl_xor(v, 2);
    v += __shfl_xor(v, 1);
    return v;
}
__device__ __forceinline__ float wsum16(float v) { // sum within 16-lane group
    v += __shfl_xor(v, 1);
    v += __shfl_xor(v, 2);
    v += __shfl_xor(v, 4);
    v += __shfl_xor(v, 8);
    return v;
}

// ---- fused setup: [0,eB): expmap rows; [eB,eB+64): zero csr_off; rest: cvt W ----
__global__ void k_setup(const float* __restrict__ x, unsigned short* __restrict__ h_bf,
                        float* __restrict__ hnorm2, int nrows,
                        int* __restrict__ csr_off, int nOff,
                        const float* __restrict__ W1, const float* __restrict__ W2,
                        unsigned short* __restrict__ w_bf, int nPerW, int eB) {
    int bid = blockIdx.x;
    if (bid < eB) {                      // h = proj(expmap0(x)) -> bf16 + |h|^2
        int gid = bid * 256 + threadIdx.x;
        int row = gid >> 6, lane = gid & 63;
        if (row >= nrows) return;
        size_t base = (size_t)row * DIM + lane * 4;
        float4 v = *(const float4*)(x + base);
        float ss = wsum(v.x * v.x + v.y * v.y + v.z * v.z + v.w * v.w);
        float n = fmaxf(sqrtf(ss), MINN);
        float tn = tanhf(n);
        float hn = (tn > MAXNORM) ? MAXNORM : tn;
        float s = hn / n;
        ushort4 ob;
        ob.x = f2bf(v.x * s); ob.y = f2bf(v.y * s);
        ob.z = f2bf(v.z * s); ob.w = f2bf(v.w * s);
        *(ushort4*)(h_bf + base) = ob;
        if (lane == 0) hnorm2[row] = hn * hn;
    } else if (bid < eB + 64) {          // zero csr_off
        int i = (bid - eB) * 256 + threadIdx.x;
        int stride = 64 * 256;
        for (; i < nOff; i += stride) csr_off[i] = 0;
    } else {                             // W1,W2 -> bf16
        int i = (bid - eB - 64) * 256 + threadIdx.x;
        int stride = 128 * 256;
        for (; i < 2 * nPerW; i += stride)
            w_bf[i] = f2bf(i < nPerW ? W1[i] : W2[i - nPerW]);
    }
}

// ======================= CSR build (once per call) =======================
__global__ void k_hist(const int* __restrict__ dst, int* __restrict__ off, int nE, int nrows) {
    int e = blockIdx.x * blockDim.x + threadIdx.x;
    if (e >= nE) return;
    int d = dst[e];
    if (d >= 0 && d < nrows) atomicAdd(&off[d + 1], 1);
}

// single-block inclusive scan in place over a[0..n-1]; also cursor[i]=a[i] (i<n-1)
__global__ void k_scan(int* __restrict__ a, int* __restrict__ cursor, int n) {
    __shared__ int wsums[16];
    int t = threadIdx.x;                 // 1024 threads
    int chunk = (n + 1023) / 1024;
    int lo = t * chunk, hi = min(lo + chunk, n);
    int sum = 0;
    for (int i = lo; i < hi; ++i) sum += a[i];
    int lane = t & 63, wid = t >> 6;
    int v = sum;
    for (int o = 1; o < 64; o <<= 1) {
        int u = __shfl_up(v, o);
        if (lane >= o) v += u;
    }
    if (lane == 63) wsums[wid] = v;
    __syncthreads();
    if (t == 0) {
        int c = 0;
        for (int i = 0; i < 16; ++i) { int x = wsums[i]; wsums[i] = c; c += x; }
    }
    __syncthreads();
    int excl = v - sum + wsums[wid];
    int c = excl;
    for (int i = lo; i < hi; ++i) {
        c += a[i];
        a[i] = c;
        if (i < n - 1) cursor[i] = c;
    }
}

__global__ void k_fill(const int* __restrict__ esrc, const int* __restrict__ edst,
                       const float* __restrict__ ew, int* __restrict__ cursor,
                       int2* __restrict__ csr_pack, int nE, int nrows) {
    int e = blockIdx.x * blockDim.x + threadIdx.x;
    if (e >= nE) return;
    int d = edst[e];
    if (d < 0 || d >= nrows) return;
    int pos = atomicAdd(&cursor[d], 1);
    csr_pack[pos] = make_int2(esrc[e], __float_as_int(ew[e]));
}

// ---- fused GEMM + HypLinear-post, block-scope: 512 threads = 8 waves per
// 16-row stripe; wave w owns j-tiles {2w, 2w+1} (cols [32w, 32w+32)).
// MFMA indexing verified in R11 (passed, absmax identical to split version).
// Row scalars: wsum16 partials over each wave's 32 cols + LDS cross-wave sum.
__global__ void k_gemm_post(const unsigned short* __restrict__ Abf,
                            const unsigned short* __restrict__ Wbf,
                            const float* __restrict__ hnorm2,
                            const float* __restrict__ b,
                            unsigned short* __restrict__ XT, int M) {
    __shared__ float sm_part[8][16];
    __shared__ float sxy_part[8][16];
    int wave = threadIdx.x >> 6;         // 0..7
    int lane = threadIdx.x & 63;
    int r = lane & 15, oct = lane >> 4;
    int i0 = blockIdx.x * 16;
    int arow = i0 + r;
    bool av = arow < M;
    const unsigned short* ap = Abf + (size_t)arow * DIM + oct * 8;
    const bf16x8 zf = {0, 0, 0, 0, 0, 0, 0, 0};
    bf16x8 afrag[8];
#pragma unroll
    for (int kc = 0; kc < 8; ++kc)
        afrag[kc] = av ? *(const bf16x8*)(ap + kc * 32) : zf;

    int jbase = wave * 32;
    f32x4 acc[2];
#pragma unroll
    for (int t = 0; t < 2; ++t) {
        acc[t] = (f32x4){0.f, 0.f, 0.f, 0.f};
        const unsigned short* bp = Wbf + (size_t)(jbase + t * 16 + r) * DIM + oct * 8;
#pragma unroll
        for (int kc = 0; kc < 8; ++kc) {
            bf16x8 bb = *(const bf16x8*)(bp + kc * 32);
            acc[t] = __builtin_amdgcn_mfma_f32_16x16x32_bf16(afrag[kc], bb, acc[t], 0, 0, 0);
        }
    }

    // bias norm over ALL 256 cols via 64-lane wsum (each lane covers 4 cols)
    float4 bq = *(const float4*)(b + lane * 4);
    float bss = wsum(bq.x * bq.x + bq.y * bq.y + bq.z * bq.z + bq.w * bq.w);
    float bn = fmaxf(sqrtf(bss), MINN);
    float btn = tanhf(bn);
    float bhn = (btn > MAXNORM) ? MAXNORM : btn;
    float bscale = bhn / bn;
    float y2 = bhn * bhn;
    // wave-local bias cols
    float bv[2];
#pragma unroll
    for (int t = 0; t < 2; ++t) bv[t] = b[jbase + t * 16 + r];

    // per-row partials over this wave's 32 cols
#pragma unroll
    for (int q = 0; q < 4; ++q) {
        float smv = 0.f, dotv = 0.f;
#pragma unroll
        for (int t = 0; t < 2; ++t) {
            float m = acc[t][q];
            smv = fmaf(m, m, smv);
            dotv = fmaf(m, bv[t], dotv);
        }
        smv = wsum16(smv);
        dotv = wsum16(dotv);
        if (r == 0) {
            sm_part[wave][oct * 4 + q] = smv;
            sxy_part[wave][oct * 4 + q] = dotv;
        }
    }
    __syncthreads();

#pragma unroll
    for (int q = 0; q < 4; ++q) {
        int lr = oct * 4 + q;
        float sm = 0.f, sxyr = 0.f;
#pragma unroll
        for (int w = 0; w < 8; ++w) { sm += sm_part[w][lr]; sxyr += sxy_part[w][lr]; }
        float sxy = sxyr * bscale;
        int R = i0 + lr;
        float sh = (R < M) ? hnorm2[R] : 1.0f;
        float xn = fmaxf(sqrtf(sh), MINN);
        float at = atanhf(fminf(xn, CLIPV));
        float mn = fmaxf(sqrtf(sm), MINN);
        float t = tanhf(mn / xn * at);
        float alpha = t / mn;            // res = alpha * mx
        float resn = t;
        if (t > MAXNORM) { alpha = MAXNORM / mn; resn = MAXNORM; }
        float x2 = resn * resn;
        float xy = alpha * sxy;          // res . bias
        float Aa = 1.f + 2.f * xy + y2;
        float Bb = 1.f - x2;
        float den = fmaxf(1.f + 2.f * xy + x2 * y2, MINN);
        float s_m = Aa * alpha / den;    // hout = s_m*mx + s_b*bias
        float s_b = Bb / den;
        float hn2 = (Aa * Aa * x2 + 2.f * Aa * Bb * xy + Bb * Bb * y2) / (den * den);
        float hn = fmaxf(sqrtf(fmaxf(hn2, 0.f)), MINN);
        if (hn > MAXNORM) { float f = MAXNORM / hn; s_m *= f; s_b *= f; hn = MAXNORM; }
        float lt = atanhf(fminf(hn, CLIPV)) / hn;  // logmap0 scale
        s_m *= lt; s_b *= lt;
        if (R < M) {
            unsigned short* op = XT + (size_t)R * DIM + jbase + r;
#pragma unroll
            for (int t2 = 0; t2 < 2; ++t2)
                op[t2 * 16] = f2h(fmaf(s_m, acc[t2][q], s_b * (bscale * bv[t2])));
        }
    }
}

// ---- fused CSR aggregation + FULL finish: one wave per dst row ----
// agg = sum w*xt[src]; h=proj(expmap0(agg)); xt2=relu(logmap0(h));
// o = proj(expmap0(xt2)). Mid-layer: bf16(o) + |o|^2; final: fp32(o).
__global__ void k_agg_finish(const unsigned short* __restrict__ XT, const int* __restrict__ off,
                             const int2* __restrict__ cpk,
                             float* __restrict__ OUT, unsigned short* __restrict__ OUT_bf,
                             float* __restrict__ hnorm2, int nrows) {
    int gid = blockIdx.x * blockDim.x + threadIdx.x;
    int row = gid >> 6, lane = gid & 63;
    if (row >= nrows) return;
    int p0 = off[row], p1 = off[row + 1];
    float a0 = 0.f, a1 = 0.f, a2 = 0.f, a3 = 0.f;
    int p = p0;
    for (; p + 7 < p1; p += 8) {
        ushort4 v[8];
        float w[8];
#pragma unroll
        for (int u = 0; u < 8; ++u) {
            int2 pk = cpk[p + u];
            w[u] = __int_as_float(pk.y);
            v[u] = *(const ushort4*)(XT + (size_t)pk.x * DIM + lane * 4);
        }
#pragma unroll
        for (int u = 0; u < 8; ++u) {
            a0 = fmaf(w[u], h2f(v[u].x), a0);
            a1 = fmaf(w[u], h2f(v[u].y), a1);
            a2 = fmaf(w[u], h2f(v[u].z), a2);
            a3 = fmaf(w[u], h2f(v[u].w), a3);
        }
    }
    for (; p < p1; ++p) {
        int2 pk = cpk[p];
        float w = __int_as_float(pk.y);
        ushort4 v = *(const ushort4*)(XT + (size_t)pk.x * DIM + lane * 4);
        a0 = fmaf(w, h2f(v.x), a0); a1 = fmaf(w, h2f(v.y), a1);
        a2 = fmaf(w, h2f(v.z), a2); a3 = fmaf(w, h2f(v.w), a3);
    }
    float ss = wsum(a0 * a0 + a1 * a1 + a2 * a2 + a3 * a3);
    float n = fmaxf(sqrtf(ss), MINN);
    float tn = tanhf(n);
    float hn = (tn > MAXNORM) ? MAXNORM : tn;
    float s1 = hn / n;                              // h = s1*agg
    float lt = atanhf(fminf(hn, CLIPV)) / fmaxf(hn, MINN);
    float s2 = lt * s1;                             // logmap0(h) = s2*agg
    float x0 = fmaxf(s2 * a0, 0.f), x1 = fmaxf(s2 * a1, 0.f);
    float x2 = fmaxf(s2 * a2, 0.f), x3 = fmaxf(s2 * a3, 0.f);
    float ss2 = wsum(x0 * x0 + x1 * x1 + x2 * x2 + x3 * x3);
    float n2 = fmaxf(sqrtf(ss2), MINN);
    float tn2 = tanhf(n2);
    float hn2c = (tn2 > MAXNORM) ? MAXNORM : tn2;
    float s3 = hn2c / n2;                           // o = s3 * relu(...)
    float o0 = s3 * x0, o1 = s3 * x1, o2 = s3 * x2, o3 = s3 * x3;
    size_t base = (size_t)row * DIM + lane * 4;
    if (OUT_bf) {                        // mid-layer: emit bf16 o + |o|^2
        ushort4 ob;
        ob.x = f2bf(o0); ob.y = f2bf(o1); ob.z = f2bf(o2); ob.w = f2bf(o3);
        *(ushort4*)(OUT_bf + base) = ob;
        if (lane == 0) hnorm2[row] = hn2c * hn2c;
    } else {                             // final layer: fp32 out
        *(float4*)(OUT + base) = make_float4(o0, o1, o2, o3);
    }
}

static inline size_t align256(size_t x) { return (x + 255) & ~(size_t)255; }

extern "C" void kernel_launch(void* const* d_in, const int* in_sizes, int n_in,
                              void* d_out, int out_size, void* d_ws, size_t ws_size,
                              hipStream_t stream) {
    const float* x  = (const float*)d_in[0];
    const float* W1 = (const float*)d_in[1];
    const float* b1 = (const float*)d_in[2];
    const float* W2 = (const float*)d_in[3];
    const float* b2 = (const float*)d_in[4];
    const float* ew = (const float*)d_in[5];
    const int* esrc = (const int*)d_in[6];
    const int* edst = (const int*)d_in[7];
    const int nE = in_sizes[5];
    const int M  = in_sizes[0] / DIM;   // 10000

    size_t S = (size_t)M * DIM;         // elements per N x D buffer
    char* base = (char*)d_ws;
    size_t o = 0;
    int2* csr_pack = (int2*)(base + o);          o = align256(o + (size_t)nE * 8);
    int* csr_off   = (int*)(base + o);           o = align256(o + (size_t)(M + 1) * 4);
    int* cursor    = (int*)(base + o);           o = align256(o + (size_t)M * 4);
    float* hnorm2  = (float*)(base + o);         o = align256(o + (size_t)(M + 64) * 4);
    unsigned short* xt   = (unsigned short*)(base + o);  o = align256(o + S * 2);
    unsigned short* h_bf = (unsigned short*)(base + o);  o = align256(o + S * 2);
    unsigned short* w_bf = (unsigned short*)(base + o);  o = align256(o + (size_t)2 * DIM * DIM * 2);

    int rowBlocks = (M + 3) / 4;        // 4 waves (rows) per 256-thread block
    int stripeBlocks = (M + 15) / 16;   // one 16-row stripe per 512-thread block
    int edgeBlocks = (nE + 255) / 256;

    // ---- fused setup: expmap_in + zero(csr_off) + cvt W (one dispatch) ----
    k_setup<<<rowBlocks + 64 + 128, 256, 0, stream>>>(
        x, h_bf, hnorm2, M, csr_off, M + 1, W1, W2, w_bf, DIM * DIM, rowBlocks);

    // ---- build CSR by dst: 3 dispatches ----
    k_hist<<<edgeBlocks, 256, 0, stream>>>(edst, csr_off, nE, M);
    k_scan<<<1, 1024, 0, stream>>>(csr_off, cursor, M + 1);
    k_fill<<<edgeBlocks, 256, 0, stream>>>(esrc, edst, ew, cursor, csr_pack, nE, M);

    for (int layer = 0; layer < 2; ++layer) {
        const float* b = (layer == 0) ? b1 : b2;
        const unsigned short* Wb = w_bf + (size_t)layer * DIM * DIM;
        k_gemm_post<<<stripeBlocks, 512, 0, stream>>>(h_bf, Wb, hnorm2, b, xt, M);
        k_agg_finish<<<rowBlocks, 256, 0, stream>>>(
            xt, csr_off, csr_pack,
            (layer == 0) ? (float*)nullptr : (float*)d_out,
            (layer == 0) ? h_bf : (unsigned short*)nullptr,
            hnorm2, M);
    }
}

// Round 14
// 243.651 us; speedup vs baseline: 1.0109x; 1.0109x over previous
//
#include <hip/hip_runtime.h>
#include <hip/hip_fp16.h>

#define DIM 256
#define MAXNORM 0.996f      // (1 - 4e-3)/sqrt(c), c=1
#define MINN 1e-15f
#define CLIPV 0.9999999f    // 1 - 1e-7

typedef __attribute__((ext_vector_type(8))) short bf16x8;
typedef __attribute__((ext_vector_type(4))) float f32x4;

__device__ __forceinline__ unsigned short f2bf(float f) {
    unsigned int u = __float_as_uint(f);
    u += 0x7fffu + ((u >> 16) & 1u);   // RNE
    return (unsigned short)(u >> 16);
}
__device__ __forceinline__ float h2f(unsigned short h) {
    return __half2float(__ushort_as_half(h));
}
__device__ __forceinline__ unsigned short f2h(float f) {
    return __half_as_ushort(__float2half(f));
}
__device__ __forceinline__ float wsum(float v) {   // 64-lane sum
    v += __shfl_xor(v, 32);
    v += __shfl_xor(v, 16);
    v += __shfl_xor(v, 8);
    v += __shfl_xor(v, 4);
    v += __shfl_xor(v, 2);
    v += __shfl_xor(v, 1);
    return v;
}

// ---- fused setup: [0,eB): expmap rows; [eB,eB+64): zero csr_off; rest: cvt W ----
__global__ void k_setup(const float* __restrict__ x, unsigned short* __restrict__ h_bf,
                        float* __restrict__ hnorm2, int nrows,
                        int* __restrict__ csr_off, int nOff,
                        const float* __restrict__ W1, const float* __restrict__ W2,
                        unsigned short* __restrict__ w_bf, int nPerW, int eB) {
    int bid = blockIdx.x;
    if (bid < eB) {                      // h = proj(expmap0(x)) -> bf16 + |h|^2
        int gid = bid * 256 + threadIdx.x;
        int row = gid >> 6, lane = gid & 63;
        if (row >= nrows) return;
        size_t base = (size_t)row * DIM + lane * 4;
        float4 v = *(const float4*)(x + base);
        float ss = wsum(v.x * v.x + v.y * v.y + v.z * v.z + v.w * v.w);
        float n = fmaxf(sqrtf(ss), MINN);
        float tn = tanhf(n);
        float hn = (tn > MAXNORM) ? MAXNORM : tn;
        float s = hn / n;
        ushort4 ob;
        ob.x = f2bf(v.x * s); ob.y = f2bf(v.y * s);
        ob.z = f2bf(v.z * s); ob.w = f2bf(v.w * s);
        *(ushort4*)(h_bf + base) = ob;
        if (lane == 0) hnorm2[row] = hn * hn;
    } else if (bid < eB + 64) {          // zero csr_off
        int i = (bid - eB) * 256 + threadIdx.x;
        int stride = 64 * 256;
        for (; i < nOff; i += stride) csr_off[i] = 0;
    } else {                             // W1,W2 -> bf16
        int i = (bid - eB - 64) * 256 + threadIdx.x;
        int stride = 128 * 256;
        for (; i < 2 * nPerW; i += stride)
            w_bf[i] = f2bf(i < nPerW ? W1[i] : W2[i - nPerW]);
    }
}

// ======================= CSR build (once per call) =======================
__global__ void k_hist(const int* __restrict__ dst, int* __restrict__ off, int nE, int nrows) {
    int e = blockIdx.x * blockDim.x + threadIdx.x;
    if (e >= nE) return;
    int d = dst[e];
    if (d >= 0 && d < nrows) atomicAdd(&off[d + 1], 1);
}

// single-block inclusive scan in place over a[0..n-1]; also cursor[i]=a[i] (i<n-1)
__global__ void k_scan(int* __restrict__ a, int* __restrict__ cursor, int n) {
    __shared__ int wsums[16];
    int t = threadIdx.x;                 // 1024 threads
    int chunk = (n + 1023) / 1024;
    int lo = t * chunk, hi = min(lo + chunk, n);
    int sum = 0;
    for (int i = lo; i < hi; ++i) sum += a[i];
    int lane = t & 63, wid = t >> 6;
    int v = sum;
    for (int o = 1; o < 64; o <<= 1) {
        int u = __shfl_up(v, o);
        if (lane >= o) v += u;
    }
    if (lane == 63) wsums[wid] = v;
    __syncthreads();
    if (t == 0) {
        int c = 0;
        for (int i = 0; i < 16; ++i) { int x = wsums[i]; wsums[i] = c; c += x; }
    }
    __syncthreads();
    int excl = v - sum + wsums[wid];
    int c = excl;
    for (int i = lo; i < hi; ++i) {
        c += a[i];
        a[i] = c;
        if (i < n - 1) cursor[i] = c;
    }
}

__global__ void k_fill(const int* __restrict__ esrc, const int* __restrict__ edst,
                       const float* __restrict__ ew, int* __restrict__ cursor,
                       int2* __restrict__ csr_pack, int nE, int nrows) {
    int e = blockIdx.x * blockDim.x + threadIdx.x;
    if (e >= nE) return;
    int d = edst[e];
    if (d < 0 || d >= nrows) return;
    int pos = atomicAdd(&cursor[d], 1);
    csr_pack[pos] = make_int2(esrc[e], __float_as_int(ew[e]));
}

// ---- MFMA GEMM: C[i][j] = sum_k A[i][k]*W[j][k], A/W bf16, C fp16, K=N=256 ----
// grid (16, ceil(M/64)), block 256 = 4 waves; wave computes a 16x16 tile, no LDS.
__global__ void k_gemm_mfma(const unsigned short* __restrict__ Abf,
                            const unsigned short* __restrict__ Wbf,
                            unsigned short* __restrict__ C16, int M) {
    int wave = threadIdx.x >> 6;
    int lane = threadIdx.x & 63;
    int r = lane & 15, oct = lane >> 4;
    int i0 = blockIdx.y * 64 + wave * 16;
    int j0 = blockIdx.x * 16;
    int arow = i0 + r;
    bool av = arow < M;
    const unsigned short* ap = Abf + (size_t)arow * DIM + oct * 8;
    const unsigned short* bp = Wbf + (size_t)(j0 + r) * DIM + oct * 8;
    const bf16x8 zf = {0, 0, 0, 0, 0, 0, 0, 0};
    f32x4 acc = {0.f, 0.f, 0.f, 0.f};
#pragma unroll
    for (int k0 = 0; k0 < 256; k0 += 32) {
        bf16x8 a = av ? *(const bf16x8*)(ap + k0) : zf;
        bf16x8 b = *(const bf16x8*)(bp + k0);
        acc = __builtin_amdgcn_mfma_f32_16x16x32_bf16(a, b, acc, 0, 0, 0);
    }
    // C/D layout: col = lane&15, row = (lane>>4)*4 + reg
#pragma unroll
    for (int q = 0; q < 4; ++q) {
        int row = i0 + oct * 4 + q;
        if (row < M) C16[(size_t)row * DIM + j0 + r] = f2h(acc[q]);
    }
}

// ---- fused: bias=proj(expmap0(b)); res=proj(mobius_matvec); mobius_add; proj; logmap0 -> XT fp16 ----
__global__ void k_post(const unsigned short* __restrict__ MX16, const float* __restrict__ hnorm2,
                       const float* __restrict__ b, unsigned short* __restrict__ XT, int nrows) {
    int gid = blockIdx.x * blockDim.x + threadIdx.x;
    int row = gid >> 6, lane = gid & 63;
    if (row >= nrows) return;
    size_t base = (size_t)row * DIM + lane * 4;
    ushort4 mu = *(const ushort4*)(MX16 + base);
    float m0 = h2f(mu.x), m1 = h2f(mu.y), m2 = h2f(mu.z), m3 = h2f(mu.w);
    float4 bv = *(const float4*)(b + lane * 4);
    // bias = proj(expmap0(b)) computed per wave (cheap)
    float bs = wsum(bv.x * bv.x + bv.y * bv.y + bv.z * bv.z + bv.w * bv.w);
    float bn = fmaxf(sqrtf(bs), MINN);
    float btn = tanhf(bn);
    float bhn = (btn > MAXNORM) ? MAXNORM : btn;
    float bscale = bhn / bn;
    float e0 = bv.x * bscale, e1 = bv.y * bscale, e2 = bv.z * bscale, e3 = bv.w * bscale;
    float y2 = bhn * bhn;

    float sm = wsum(m0 * m0 + m1 * m1 + m2 * m2 + m3 * m3);
    float sxy = wsum(m0 * e0 + m1 * e1 + m2 * e2 + m3 * e3);
    float sh = hnorm2[row];
    float xn = fmaxf(sqrtf(sh), MINN);
    float at = atanhf(fminf(xn, CLIPV));
    float mn = fmaxf(sqrtf(sm), MINN);
    float t = tanhf(mn / xn * at);
    float alpha = t / mn;            // res = alpha * mx
    float resn = t;
    if (t > MAXNORM) { alpha = MAXNORM / mn; resn = MAXNORM; }
    float x2 = resn * resn;
    float xy = alpha * sxy;          // res . bias
    float Aa = 1.f + 2.f * xy + y2;
    float Bb = 1.f - x2;
    float den = fmaxf(1.f + 2.f * xy + x2 * y2, MINN);
    float s_m = Aa * alpha / den;    // h = s_m*mx + s_b*bias
    float s_b = Bb / den;
    float hn2 = (Aa * Aa * x2 + 2.f * Aa * Bb * xy + Bb * Bb * y2) / (den * den);
    float hn = fmaxf(sqrtf(fmaxf(hn2, 0.f)), MINN);
    if (hn > MAXNORM) { float f = MAXNORM / hn; s_m *= f; s_b *= f; hn = MAXNORM; }
    float lt = atanhf(fminf(hn, CLIPV)) / hn;  // logmap0 scale
    s_m *= lt; s_b *= lt;
    ushort4 o;
    o.x = f2h(s_m * m0 + s_b * e0);
    o.y = f2h(s_m * m1 + s_b * e1);
    o.z = f2h(s_m * m2 + s_b * e2);
    o.w = f2h(s_m * m3 + s_b * e3);
    *(ushort4*)(XT + base) = o;
}

// ---- fused CSR aggregation + FULL finish: one wave per dst row ----
// agg = sum w*xt[src]; h=proj(expmap0(agg)); xt2=relu(logmap0(h));
// o = proj(expmap0(xt2)). Mid-layer: bf16(o) + |o|^2; final: fp32(o).
__global__ void k_agg_finish(const unsigned short* __restrict__ XT, const int* __restrict__ off,
                             const int2* __restrict__ cpk,
                             float* __restrict__ OUT, unsigned short* __restrict__ OUT_bf,
                             float* __restrict__ hnorm2, int nrows) {
    int gid = blockIdx.x * blockDim.x + threadIdx.x;
    int row = gid >> 6, lane = gid & 63;
    if (row >= nrows) return;
    int p0 = off[row], p1 = off[row + 1];
    float a0 = 0.f, a1 = 0.f, a2 = 0.f, a3 = 0.f;
    int p = p0;
    for (; p + 7 < p1; p += 8) {
        ushort4 v[8];
        float w[8];
#pragma unroll
        for (int u = 0; u < 8; ++u) {
            int2 pk = cpk[p + u];
            w[u] = __int_as_float(pk.y);
            v[u] = *(const ushort4*)(XT + (size_t)pk.x * DIM + lane * 4);
        }
#pragma unroll
        for (int u = 0; u < 8; ++u) {
            a0 = fmaf(w[u], h2f(v[u].x), a0);
            a1 = fmaf(w[u], h2f(v[u].y), a1);
            a2 = fmaf(w[u], h2f(v[u].z), a2);
            a3 = fmaf(w[u], h2f(v[u].w), a3);
        }
    }
    for (; p < p1; ++p) {
        int2 pk = cpk[p];
        float w = __int_as_float(pk.y);
        ushort4 v = *(const ushort4*)(XT + (size_t)pk.x * DIM + lane * 4);
        a0 = fmaf(w, h2f(v.x), a0); a1 = fmaf(w, h2f(v.y), a1);
        a2 = fmaf(w, h2f(v.z), a2); a3 = fmaf(w, h2f(v.w), a3);
    }
    float ss = wsum(a0 * a0 + a1 * a1 + a2 * a2 + a3 * a3);
    float n = fmaxf(sqrtf(ss), MINN);
    float tn = tanhf(n);
    float hn = (tn > MAXNORM) ? MAXNORM : tn;
    float s1 = hn / n;                              // h = s1*agg
    float lt = atanhf(fminf(hn, CLIPV)) / fmaxf(hn, MINN);
    float s2 = lt * s1;                             // logmap0(h) = s2*agg
    float x0 = fmaxf(s2 * a0, 0.f), x1 = fmaxf(s2 * a1, 0.f);
    float x2 = fmaxf(s2 * a2, 0.f), x3 = fmaxf(s2 * a3, 0.f);
    float ss2 = wsum(x0 * x0 + x1 * x1 + x2 * x2 + x3 * x3);
    float n2 = fmaxf(sqrtf(ss2), MINN);
    float tn2 = tanhf(n2);
    float hn2c = (tn2 > MAXNORM) ? MAXNORM : tn2;
    float s3 = hn2c / n2;                           // o = s3 * relu(...)
    float o0 = s3 * x0, o1 = s3 * x1, o2 = s3 * x2, o3 = s3 * x3;
    size_t base = (size_t)row * DIM + lane * 4;
    if (OUT_bf) {                        // mid-layer: emit bf16 o + |o|^2
        ushort4 ob;
        ob.x = f2bf(o0); ob.y = f2bf(o1); ob.z = f2bf(o2); ob.w = f2bf(o3);
        *(ushort4*)(OUT_bf + base) = ob;
        if (lane == 0) hnorm2[row] = hn2c * hn2c;
    } else {                             // final layer: fp32 out
        *(float4*)(OUT + base) = make_float4(o0, o1, o2, o3);
    }
}

static inline size_t align256(size_t x) { return (x + 255) & ~(size_t)255; }

extern "C" void kernel_launch(void* const* d_in, const int* in_sizes, int n_in,
                              void* d_out, int out_size, void* d_ws, size_t ws_size,
                              hipStream_t stream) {
    const float* x  = (const float*)d_in[0];
    const float* W1 = (const float*)d_in[1];
    const float* b1 = (const float*)d_in[2];
    const float* W2 = (const float*)d_in[3];
    const float* b2 = (const float*)d_in[4];
    const float* ew = (const float*)d_in[5];
    const int* esrc = (const int*)d_in[6];
    const int* edst = (const int*)d_in[7];
    const int nE = in_sizes[5];
    const int M  = in_sizes[0] / DIM;   // 10000

    size_t S = (size_t)M * DIM;         // elements per N x D buffer
    char* base = (char*)d_ws;
    size_t o = 0;
    int2* csr_pack = (int2*)(base + o);          o = align256(o + (size_t)nE * 8);
    int* csr_off   = (int*)(base + o);           o = align256(o + (size_t)(M + 1) * 4);
    int* cursor    = (int*)(base + o);           o = align256(o + (size_t)M * 4);
    float* hnorm2  = (float*)(base + o);         o = align256(o + (size_t)(M + 64) * 4);
    unsigned short* xt   = (unsigned short*)(base + o);  o = align256(o + S * 2);
    unsigned short* h_bf = (unsigned short*)(base + o);  o = align256(o + S * 2);
    unsigned short* mx16 = (unsigned short*)(base + o);  o = align256(o + S * 2);
    unsigned short* w_bf = (unsigned short*)(base + o);  o = align256(o + (size_t)2 * DIM * DIM * 2);

    int rowBlocks = (M + 3) / 4;        // 4 waves (rows) per 256-thread block
    dim3 gemmGrid(DIM / 16, (M + 63) / 64);
    int edgeBlocks = (nE + 255) / 256;

    // ---- fused setup: expmap_in + zero(csr_off) + cvt W (one dispatch) ----
    k_setup<<<rowBlocks + 64 + 128, 256, 0, stream>>>(
        x, h_bf, hnorm2, M, csr_off, M + 1, W1, W2, w_bf, DIM * DIM, rowBlocks);

    // ---- build CSR by dst: 3 dispatches ----
    k_hist<<<edgeBlocks, 256, 0, stream>>>(edst, csr_off, nE, M);
    k_scan<<<1, 1024, 0, stream>>>(csr_off, cursor, M + 1);
    k_fill<<<edgeBlocks, 256, 0, stream>>>(esrc, edst, ew, cursor, csr_pack, nE, M);

    for (int layer = 0; layer < 2; ++layer) {
        const float* b = (layer == 0) ? b1 : b2;
        const unsigned short* Wb = w_bf + (size_t)layer * DIM * DIM;
        k_gemm_mfma<<<gemmGrid, 256, 0, stream>>>(h_bf, Wb, mx16, M);
        k_post<<<rowBlocks, 256, 0, stream>>>(mx16, hnorm2, b, xt, M);
        k_agg_finish<<<rowBlocks, 256, 0, stream>>>(
            xt, csr_off, csr_pack,
            (layer == 0) ? (float*)nullptr : (float*)d_out,
            (layer == 0) ? h_bf : (unsigned short*)nullptr,
            hnorm2, M);
    }
}